// Round 1
// baseline (162.538 us; speedup 1.0000x reference)
//
#include <hip/hip_runtime.h>
#include <stdint.h>

// Problem: B=4, T=4096, C=256, H=64, non-causal softmax attention (eval mode).
// out fp32 [4,4096,64]. Scale = C^-0.5 = 1/16, folded (with log2e) into Wq/bq.

#define TSEQ 4096
#define CEMB 256
#define HD   64
#define QK_SCALE 0.09016844005555021f   // log2(e) / 16

typedef short short8 __attribute__((ext_vector_type(8)));
typedef float f32x4 __attribute__((ext_vector_type(4)));

static __device__ __forceinline__ unsigned short f2bf(float f){
  unsigned u = __builtin_bit_cast(unsigned, f);
  u += 0x7fffu + ((u >> 16) & 1u);           // RNE
  return (unsigned short)(u >> 16);
}
static __device__ __forceinline__ float fexp2(float x){
  float r; asm("v_exp_f32 %0, %1" : "=v"(r) : "v"(x)); return r;
}

// ---------------- kernel 0: pack weights bf16, transposed [j][n][k] ----------
__global__ __launch_bounds__(256) void pack_w_k(const float* __restrict__ Wk,
    const float* __restrict__ Wq, const float* __restrict__ Wv,
    unsigned short* __restrict__ wt){
  int j = blockIdx.x >> 6;            // 0:K 1:Q 2:V
  int n = blockIdx.x & 63;
  int k = threadIdx.x;                // 0..255
  const float* W = (j==0) ? Wk : ((j==1) ? Wq : Wv);
  float s = (j==1) ? QK_SCALE : 1.0f;
  wt[j*16384 + n*256 + k] = f2bf(W[k*64 + n] * s);
}

// ---------------- kernel 1: QKV projection ----------------------------------
// grid 256: each block 64 rows of flat [16384][256] x. Q,K row-major bf16;
// V written transposed to [B][64][T] bf16 (LDS bounce for coalescing).
__global__ __launch_bounds__(256) void qkv_proj_k(const float* __restrict__ x,
    const float* __restrict__ bk, const float* __restrict__ bq,
    const unsigned short* __restrict__ wt,
    unsigned short* __restrict__ qw, unsigned short* __restrict__ kw,
    unsigned short* __restrict__ vtw){
  __shared__ __align__(16) unsigned char xl[32768];   // [64][256] bf16 swizzled
  __shared__ __align__(16) unsigned short vb[64*72];  // V bounce, ld=72
  const int tid = threadIdx.x;
  const int r0 = blockIdx.x << 6;

  #pragma unroll
  for (int i=0;i<16;++i){
    int f4 = tid + (i<<8);                       // 0..4095 float4 of tile
    float4 v = ((const float4*)x)[((size_t)r0<<6) + f4];
    int row = f4 >> 6;
    int byt = ((row<<9) + ((f4&63)<<3)) ^ ((row&7)<<4);
    unsigned long long pk = (unsigned long long)f2bf(v.x)
      | ((unsigned long long)f2bf(v.y)<<16)
      | ((unsigned long long)f2bf(v.z)<<32)
      | ((unsigned long long)f2bf(v.w)<<48);
    *(unsigned long long*)(xl + byt) = pk;
  }
  __syncthreads();

  const int l = tid & 63, w = tid >> 6, g = l >> 4, c = l & 15;
  f32x4 acc[12];
  #pragma unroll
  for (int i=0;i<12;++i) acc[i] = (f32x4){0.f,0.f,0.f,0.f};

  #pragma unroll
  for (int kk=0;kk<8;++kk){
    int arow = (w<<4) + c;
    short8 a = *(const short8*)(xl + (((arow<<9) + (kk<<6) + (g<<4)) ^ ((arow&7)<<4)));
    #pragma unroll
    for (int jn=0;jn<12;++jn){
      int j = jn>>2, n = jn&3;
      short8 bf = *(const short8*)(wt + (size_t)j*16384 + (((n<<4)+c)<<8) + (kk<<5) + (g<<3));
      acc[jn] = __builtin_amdgcn_mfma_f32_16x16x32_bf16(a, bf, acc[jn], 0, 0, 0);
    }
  }

  #pragma unroll
  for (int n=0;n<4;++n){
    float bK = bk[(n<<4)+c];
    float bQ = bq[(n<<4)+c] * QK_SCALE;
    #pragma unroll
    for (int r=0;r<4;++r){
      size_t grow = (size_t)r0 + (w<<4) + (g<<2) + r;
      kw[(grow<<6) + (n<<4) + c] = f2bf(acc[n][r]   + bK);
      qw[(grow<<6) + (n<<4) + c] = f2bf(acc[4+n][r] + bQ);
    }
  }
  // V: bounce through LDS, store transposed
  #pragma unroll
  for (int n=0;n<4;++n)
    #pragma unroll
    for (int r=0;r<4;++r)
      vb[((w<<4)+(g<<2)+r)*72 + (n<<4) + c] = f2bf(acc[8+n][r]);
  __syncthreads();
  int d = tid >> 2, sg = tid & 3;
  unsigned v32[8];
  #pragma unroll
  for (int i=0;i<8;++i){
    unsigned lo = vb[((sg<<4)+(i<<1))*72 + d];
    unsigned hi = vb[((sg<<4)+(i<<1)+1)*72 + d];
    v32[i] = lo | (hi<<16);
  }
  int b = r0 >> 12, t = r0 & 4095;
  unsigned* vp = (unsigned*)(vtw + (((size_t)(b<<6) + d)<<12) + t + (sg<<4));
  uint4 o0; o0.x=v32[0]; o0.y=v32[1]; o0.z=v32[2]; o0.w=v32[3];
  uint4 o1; o1.x=v32[4]; o1.y=v32[5]; o1.z=v32[6]; o1.w=v32[7];
  ((uint4*)vp)[0] = o0;
  ((uint4*)vp)[1] = o1;
}

// ---------------- kernel 2: flash attention, 2-way key split ----------------
// grid 256 = 128 Q-blocks (128 rows) x 2 splits. 4 waves x 32 Q-rows.
// LDS: K dbuf 2x8KB | Vt dbuf 2x8KB | P 4x4KB. All 128B-row tiles XOR-swizzled.
__global__ __launch_bounds__(256) void attn_k(const unsigned short* __restrict__ qw,
    const unsigned short* __restrict__ kw, const unsigned short* __restrict__ vtw,
    float* __restrict__ opart, float* __restrict__ mpart, float* __restrict__ lpart){
  __shared__ __align__(16) unsigned char smem[49152];
  unsigned char* kl = smem;
  unsigned char* vl = smem + 16384;
  const int tid = threadIdx.x;
  const int l = tid & 63, w = tid >> 6, g = l >> 4, c = l & 15;
  unsigned char* plw = smem + 32768 + (w<<12);

  const int bx = blockIdx.x;
  const int split = bx & 1, qb = bx >> 1;
  const int b = qb >> 5;
  const int tq0 = (qb & 31) << 7;
  const int kt0 = split << 5;

  short8 qa[2][2];
  #pragma unroll
  for (int mt=0;mt<2;++mt)
    #pragma unroll
    for (int kk=0;kk<2;++kk)
      qa[mt][kk] = *(const short8*)(qw +
        ((size_t)((b<<12) + tq0 + (w<<5) + (mt<<4) + c)<<6) + (kk<<5) + (g<<3));

  f32x4 o[2][4];
  float mrow[2][4], lrow[2][4];
  #pragma unroll
  for (int mt=0;mt<2;++mt){
    #pragma unroll
    for (int n=0;n<4;++n) o[mt][n] = (f32x4){0.f,0.f,0.f,0.f};
    #pragma unroll
    for (int r=0;r<4;++r){ mrow[mt][r] = -1e30f; lrow[mt][r] = 0.f; }
  }

  uint4 rk[2], rv[2];
  // prologue: stage tile kt0 into buf 0
  #pragma unroll
  for (int u=0;u<2;++u){
    int ci = tid + (u<<8);
    int row = ci >> 3;
    int colp = ((ci&7) ^ (row&7)) << 3;      // inverse-swizzled source col
    rk[u] = *(const uint4*)(kw + ((size_t)((b<<12) + (kt0<<6) + row)<<6) + colp);
    rv[u] = *(const uint4*)(vtw + (((size_t)(b<<6) + row)<<12) + (kt0<<6) + colp);
  }
  #pragma unroll
  for (int u=0;u<2;++u){
    int ci = tid + (u<<8);
    *(uint4*)(kl + ci*16) = rk[u];
    *(uint4*)(vl + ci*16) = rv[u];
  }
  __syncthreads();

  for (int it=0; it<32; ++it){
    const int buf = it & 1;
    if (it < 31){
      int kt = kt0 + it + 1;
      #pragma unroll
      for (int u=0;u<2;++u){
        int ci = tid + (u<<8);
        int row = ci >> 3;
        int colp = ((ci&7) ^ (row&7)) << 3;
        rk[u] = *(const uint4*)(kw + ((size_t)((b<<12) + (kt<<6) + row)<<6) + colp);
        rv[u] = *(const uint4*)(vtw + (((size_t)(b<<6) + row)<<12) + (kt<<6) + colp);
      }
    }
    const unsigned char* kb_ = kl + (buf<<13);
    const unsigned char* vb_ = vl + (buf<<13);

    // --- QK^T ---
    f32x4 s[2][4];
    #pragma unroll
    for (int mt=0;mt<2;++mt)
      #pragma unroll
      for (int n=0;n<4;++n) s[mt][n] = (f32x4){0.f,0.f,0.f,0.f};
    #pragma unroll
    for (int kk=0;kk<2;++kk){
      #pragma unroll
      for (int n=0;n<4;++n){
        int row = (n<<4) + c;
        short8 kf = *(const short8*)(kb_ + (((row<<7) + (kk<<6) + (g<<4)) ^ ((row&7)<<4)));
        s[0][n] = __builtin_amdgcn_mfma_f32_16x16x32_bf16(qa[0][kk], kf, s[0][n], 0,0,0);
        s[1][n] = __builtin_amdgcn_mfma_f32_16x16x32_bf16(qa[1][kk], kf, s[1][n], 0,0,0);
      }
    }

    // --- online softmax (exp2 domain; scale pre-folded into Q) ---
    #pragma unroll
    for (int mt=0;mt<2;++mt){
      #pragma unroll
      for (int r=0;r<4;++r){
        float t0 = fmaxf(fmaxf(s[mt][0][r], s[mt][1][r]), fmaxf(s[mt][2][r], s[mt][3][r]));
        t0 = fmaxf(t0, __shfl_xor(t0,1));
        t0 = fmaxf(t0, __shfl_xor(t0,2));
        t0 = fmaxf(t0, __shfl_xor(t0,4));
        t0 = fmaxf(t0, __shfl_xor(t0,8));
        float mo = mrow[mt][r];
        float mn = fmaxf(mo, t0);
        mrow[mt][r] = mn;
        float al = fexp2(mo - mn);
        float ps = 0.f;
        int prow = (mt<<4) + (g<<2) + r;
        #pragma unroll
        for (int n=0;n<4;++n){
          float p = fexp2(s[mt][n][r] - mn);
          ps += p;
          int byt = ((prow<<7) + (((n<<4)+c)<<1)) ^ ((prow&7)<<4);
          *(unsigned short*)(plw + byt) = f2bf(p);
        }
        lrow[mt][r] = lrow[mt][r]*al + ps;        // per-lane partial row-sum
        o[mt][0][r]*=al; o[mt][1][r]*=al; o[mt][2][r]*=al; o[mt][3][r]*=al;
      }
    }

    // --- PV ---
    #pragma unroll
    for (int kk=0;kk<2;++kk){
      short8 pa[2];
      #pragma unroll
      for (int mt=0;mt<2;++mt){
        int row = (mt<<4) + c;
        pa[mt] = *(const short8*)(plw + (((row<<7) + (kk<<6) + (g<<4)) ^ ((row&7)<<4)));
      }
      #pragma unroll
      for (int n=0;n<4;++n){
        int row = (n<<4) + c;
        short8 vf = *(const short8*)(vb_ + (((row<<7) + (kk<<6) + (g<<4)) ^ ((row&7)<<4)));
        o[0][n] = __builtin_amdgcn_mfma_f32_16x16x32_bf16(pa[0], vf, o[0][n], 0,0,0);
        o[1][n] = __builtin_amdgcn_mfma_f32_16x16x32_bf16(pa[1], vf, o[1][n], 0,0,0);
      }
    }

    // write next tile into the other buffer
    if (it < 31){
      #pragma unroll
      for (int u=0;u<2;++u){
        int ci = tid + (u<<8);
        *(uint4*)(kl + ((buf^1)<<13) + ci*16) = rk[u];
        *(uint4*)(vl + ((buf^1)<<13) + ci*16) = rv[u];
      }
    }
    asm volatile("s_waitcnt vmcnt(0)" ::: "memory");
    __syncthreads();
  }

  // epilogue: unnormalized partials + (m, l)
  const int browbase = (b<<12) + tq0 + (w<<5);
  #pragma unroll
  for (int mt=0;mt<2;++mt){
    #pragma unroll
    for (int r=0;r<4;++r){
      float ls = lrow[mt][r];
      ls += __shfl_xor(ls,1);
      ls += __shfl_xor(ls,2);
      ls += __shfl_xor(ls,4);
      ls += __shfl_xor(ls,8);
      int grow = browbase + (mt<<4) + (g<<2) + r;
      if (c == 0){
        mpart[split*16384 + grow] = mrow[mt][r];
        lpart[split*16384 + grow] = ls;
      }
      #pragma unroll
      for (int n=0;n<4;++n)
        opart[((size_t)split<<20) + ((size_t)grow<<6) + (n<<4) + c] = o[mt][n][r];
    }
  }
}

// ---------------- kernel 3: combine the two key-splits ----------------------
__global__ __launch_bounds__(256) void combine_k(const float* __restrict__ opart,
    const float* __restrict__ mpart, const float* __restrict__ lpart,
    float* __restrict__ out){
  int idx = blockIdx.x*256 + threadIdx.x;       // 0 .. 1048575
  int row = idx >> 6;
  float m0 = mpart[row], m1 = mpart[16384 + row];
  float l0 = lpart[row], l1 = lpart[16384 + row];
  float mm = fmaxf(m0, m1);
  float a0 = fexp2(m0 - mm), a1 = fexp2(m1 - mm);
  out[idx] = (opart[idx]*a0 + opart[1048576 + idx]*a1) / (l0*a0 + l1*a1);
}

extern "C" void kernel_launch(void* const* d_in, const int* in_sizes, int n_in,
                              void* d_out, int out_size, void* d_ws, size_t ws_size,
                              hipStream_t stream){
  const float* x  = (const float*)d_in[0];
  const float* Wk = (const float*)d_in[1];
  const float* bk = (const float*)d_in[2];
  const float* Wq = (const float*)d_in[3];
  const float* bq = (const float*)d_in[4];
  const float* Wv = (const float*)d_in[5];
  unsigned char* ws = (unsigned char*)d_ws;
  // ws layout (needs ~14.4 MB)
  unsigned short* wt   = (unsigned short*)(ws);
  unsigned short* qw   = (unsigned short*)(ws + 131072);
  unsigned short* kw   = (unsigned short*)(ws + 131072 + 2097152);
  unsigned short* vtw  = (unsigned short*)(ws + 131072 + 2u*2097152);
  float* opart = (float*)(ws + 131072 + 3u*2097152);
  float* mpart = (float*)(ws + 131072 + 3u*2097152 + 8388608);
  float* lpart = (float*)(ws + 131072 + 3u*2097152 + 8388608 + 131072);
  float* out = (float*)d_out;

  hipLaunchKernelGGL(pack_w_k,   dim3(192),  dim3(256), 0, stream, Wk, Wq, Wv, wt);
  hipLaunchKernelGGL(qkv_proj_k, dim3(256),  dim3(256), 0, stream, x, bk, bq, wt, qw, kw, vtw);
  hipLaunchKernelGGL(attn_k,     dim3(256),  dim3(256), 0, stream, qw, kw, vtw, opart, mpart, lpart);
  hipLaunchKernelGGL(combine_k,  dim3(4096), dim3(256), 0, stream, opart, mpart, lpart, out);
}

// Round 3
// 161.396 us; speedup vs baseline: 1.0071x; 1.0071x over previous
//
#include <hip/hip_runtime.h>
#include <stdint.h>

// Problem: B=4, T=4096, C=256, H=64, non-causal softmax attention (eval mode).
// out fp32 [4,4096,64]. Scale = C^-0.5 = 1/16, folded (with log2e) into Wq/bq.

#define QK_SCALE 0.09016844005555021f   // log2(e) / 16

typedef short short8 __attribute__((ext_vector_type(8)));
typedef float f32x4 __attribute__((ext_vector_type(4)));

static __device__ __forceinline__ unsigned short f2bf(float f){
  unsigned u = __builtin_bit_cast(unsigned, f);
  u += 0x7fffu + ((u >> 16) & 1u);           // RNE
  return (unsigned short)(u >> 16);
}
static __device__ __forceinline__ float fexp2(float x){
  float r; asm("v_exp_f32 %0, %1" : "=v"(r) : "v"(x)); return r;
}

// ---------------- kernel 0: pack weights bf16, transposed [j][n][k] ----------
__global__ __launch_bounds__(256) void pack_w_k(const float* __restrict__ Wk,
    const float* __restrict__ Wq, const float* __restrict__ Wv,
    unsigned short* __restrict__ wt){
  int j = blockIdx.x >> 6;            // 0:K 1:Q 2:V
  int n = blockIdx.x & 63;
  int k = threadIdx.x;                // 0..255
  const float* W = (j==0) ? Wk : ((j==1) ? Wq : Wv);
  float s = (j==1) ? QK_SCALE : 1.0f;
  wt[j*16384 + n*256 + k] = f2bf(W[k*64 + n] * s);
}

// ---------------- kernel 1: QKV projection ----------------------------------
// grid 512: each block 32 rows of flat [16384][256] x. 4 waves: (row-half mt,
// 6 of 12 outputs). Q,K row-major bf16; V transposed to [B][64][T] bf16.
__global__ __launch_bounds__(256) void qkv_proj_k(const float* __restrict__ x,
    const float* __restrict__ bk, const float* __restrict__ bq,
    const unsigned short* __restrict__ wt,
    unsigned short* __restrict__ qw, unsigned short* __restrict__ kw,
    unsigned short* __restrict__ vtw){
  __shared__ __align__(16) unsigned char xl[16384];   // [32][256] bf16 swizzled
  __shared__ __align__(16) unsigned short vb[32*72];  // V bounce, ld=72
  const int tid = threadIdx.x;
  const int r0 = blockIdx.x << 5;

  #pragma unroll
  for (int i=0;i<8;++i){
    int f4 = tid + (i<<8);                       // 0..2047 float4 of tile
    float4 v = ((const float4*)x)[((size_t)r0<<6) + f4];
    int row = f4 >> 6;
    int byt = ((row<<9) + ((f4&63)<<3)) ^ ((row&7)<<4);
    unsigned long long pk = (unsigned long long)f2bf(v.x)
      | ((unsigned long long)f2bf(v.y)<<16)
      | ((unsigned long long)f2bf(v.z)<<32)
      | ((unsigned long long)f2bf(v.w)<<48);
    *(unsigned long long*)(xl + byt) = pk;
  }
  __syncthreads();

  const int l = tid & 63, w = tid >> 6, g = l >> 4, c = l & 15;
  const int mt = w & 1;            // row half: rows mt*16..mt*16+15
  const int jn0 = (w >> 1) * 6;    // 6 of the 12 (j,n) outputs
  f32x4 acc[6];
  #pragma unroll
  for (int i=0;i<6;++i) acc[i] = (f32x4){0.f,0.f,0.f,0.f};

  #pragma unroll
  for (int kk=0;kk<8;++kk){
    int arow = (mt<<4) + c;
    short8 a = *(const short8*)(xl + (((arow<<9) + (kk<<6) + (g<<4)) ^ ((arow&7)<<4)));
    #pragma unroll
    for (int u=0;u<6;++u){
      int jn = jn0 + u, j = jn>>2, n = jn&3;
      short8 bf = *(const short8*)(wt + (size_t)j*16384 + (((n<<4)+c)<<8) + (kk<<5) + (g<<3));
      acc[u] = __builtin_amdgcn_mfma_f32_16x16x32_bf16(a, bf, acc[u], 0, 0, 0);
    }
  }

  #pragma unroll
  for (int u=0;u<6;++u){
    int jn = jn0 + u, j = jn>>2, n = jn&3;
    if (j == 0){
      float bK = bk[(n<<4)+c];
      #pragma unroll
      for (int r=0;r<4;++r){
        size_t grow = (size_t)r0 + (mt<<4) + (g<<2) + r;
        kw[(grow<<6) + (n<<4) + c] = f2bf(acc[u][r] + bK);
      }
    } else if (j == 1){
      float bQ = bq[(n<<4)+c] * QK_SCALE;
      #pragma unroll
      for (int r=0;r<4;++r){
        size_t grow = (size_t)r0 + (mt<<4) + (g<<2) + r;
        qw[(grow<<6) + (n<<4) + c] = f2bf(acc[u][r] + bQ);
      }
    } else {
      #pragma unroll
      for (int r=0;r<4;++r)
        vb[((mt<<4)+(g<<2)+r)*72 + (n<<4) + c] = f2bf(acc[u][r]);
    }
  }
  __syncthreads();
  // transpose out: 64 d-rows x 32 t, each thread one uint4 (8 t)
  int d = tid >> 2, q = tid & 3;
  unsigned v32[4];
  #pragma unroll
  for (int i=0;i<4;++i){
    unsigned lo = vb[(q*8 + (i<<1))*72 + d];
    unsigned hi = vb[(q*8 + (i<<1) + 1)*72 + d];
    v32[i] = lo | (hi<<16);
  }
  int b = r0 >> 12, t = r0 & 4095;
  uint4 o0; o0.x=v32[0]; o0.y=v32[1]; o0.z=v32[2]; o0.w=v32[3];
  *(uint4*)(vtw + (((size_t)(b<<6) + d)<<12) + t + (q<<3)) = o0;
}

// ---------------- kernel 2: flash attention, N-way key split ----------------
// grid (128, SPLITS): 128 Q-blocks (128 rows) x SPLITS. 4 waves x 32 Q-rows.
// LDS: K dbuf 2x8KB | Vt dbuf 2x8KB | P 4x4KB. All 128B-row tiles XOR-swizzled.
__global__ __launch_bounds__(256) void attn_k(const unsigned short* __restrict__ qw,
    const unsigned short* __restrict__ kw, const unsigned short* __restrict__ vtw,
    float* __restrict__ opart, float* __restrict__ mpart, float* __restrict__ lpart,
    int ntiles){
  __shared__ __align__(16) unsigned char smem[49152];
  unsigned char* kl = smem;
  unsigned char* vl = smem + 16384;
  const int tid = threadIdx.x;
  const int l = tid & 63, w = tid >> 6, g = l >> 4, c = l & 15;
  unsigned char* plw = smem + 32768 + (w<<12);

  const int qb = blockIdx.x, split = blockIdx.y;
  const int b = qb >> 5;
  const int tq0 = (qb & 31) << 7;
  const int kt0 = split * ntiles;

  short8 qa[2][2];
  #pragma unroll
  for (int mt=0;mt<2;++mt)
    #pragma unroll
    for (int kk=0;kk<2;++kk)
      qa[mt][kk] = *(const short8*)(qw +
        ((size_t)((b<<12) + tq0 + (w<<5) + (mt<<4) + c)<<6) + (kk<<5) + (g<<3));

  f32x4 o[2][4];
  float mrow[2][4], lrow[2][4];
  #pragma unroll
  for (int mt=0;mt<2;++mt){
    #pragma unroll
    for (int n=0;n<4;++n) o[mt][n] = (f32x4){0.f,0.f,0.f,0.f};
    #pragma unroll
    for (int r=0;r<4;++r){ mrow[mt][r] = -1e30f; lrow[mt][r] = 0.f; }
  }

  uint4 rk[2], rv[2];
  // prologue: stage tile kt0 into buf 0
  #pragma unroll
  for (int u=0;u<2;++u){
    int ci = tid + (u<<8);
    int row = ci >> 3;
    int colp = ((ci&7) ^ (row&7)) << 3;      // inverse-swizzled source col
    rk[u] = *(const uint4*)(kw + ((size_t)((b<<12) + (kt0<<6) + row)<<6) + colp);
    rv[u] = *(const uint4*)(vtw + (((size_t)(b<<6) + row)<<12) + (kt0<<6) + colp);
  }
  #pragma unroll
  for (int u=0;u<2;++u){
    int ci = tid + (u<<8);
    *(uint4*)(kl + ci*16) = rk[u];
    *(uint4*)(vl + ci*16) = rv[u];
  }
  __syncthreads();

  for (int it=0; it<ntiles; ++it){
    const int buf = it & 1;
    if (it < ntiles-1){
      int kt = kt0 + it + 1;
      #pragma unroll
      for (int u=0;u<2;++u){
        int ci = tid + (u<<8);
        int row = ci >> 3;
        int colp = ((ci&7) ^ (row&7)) << 3;
        rk[u] = *(const uint4*)(kw + ((size_t)((b<<12) + (kt<<6) + row)<<6) + colp);
        rv[u] = *(const uint4*)(vtw + (((size_t)(b<<6) + row)<<12) + (kt<<6) + colp);
      }
    }
    const unsigned char* kb_ = kl + (buf<<13);
    const unsigned char* vb_ = vl + (buf<<13);

    // --- QK^T ---
    f32x4 s[2][4];
    #pragma unroll
    for (int mt=0;mt<2;++mt)
      #pragma unroll
      for (int n=0;n<4;++n) s[mt][n] = (f32x4){0.f,0.f,0.f,0.f};
    #pragma unroll
    for (int kk=0;kk<2;++kk){
      #pragma unroll
      for (int n=0;n<4;++n){
        int row = (n<<4) + c;
        short8 kf = *(const short8*)(kb_ + (((row<<7) + (kk<<6) + (g<<4)) ^ ((row&7)<<4)));
        s[0][n] = __builtin_amdgcn_mfma_f32_16x16x32_bf16(qa[0][kk], kf, s[0][n], 0,0,0);
        s[1][n] = __builtin_amdgcn_mfma_f32_16x16x32_bf16(qa[1][kk], kf, s[1][n], 0,0,0);
      }
    }

    // --- online softmax (exp2 domain; scale pre-folded into Q) ---
    #pragma unroll
    for (int mt=0;mt<2;++mt){
      #pragma unroll
      for (int r=0;r<4;++r){
        float t0 = fmaxf(fmaxf(s[mt][0][r], s[mt][1][r]), fmaxf(s[mt][2][r], s[mt][3][r]));
        t0 = fmaxf(t0, __shfl_xor(t0,1));
        t0 = fmaxf(t0, __shfl_xor(t0,2));
        t0 = fmaxf(t0, __shfl_xor(t0,4));
        t0 = fmaxf(t0, __shfl_xor(t0,8));
        float mo = mrow[mt][r];
        float mn = fmaxf(mo, t0);
        mrow[mt][r] = mn;
        float al = fexp2(mo - mn);
        float ps = 0.f;
        int prow = (mt<<4) + (g<<2) + r;
        #pragma unroll
        for (int n=0;n<4;++n){
          float p = fexp2(s[mt][n][r] - mn);
          ps += p;
          int byt = ((prow<<7) + (((n<<4)+c)<<1)) ^ ((prow&7)<<4);
          *(unsigned short*)(plw + byt) = f2bf(p);
        }
        lrow[mt][r] = lrow[mt][r]*al + ps;        // per-lane partial row-sum
        o[mt][0][r]*=al; o[mt][1][r]*=al; o[mt][2][r]*=al; o[mt][3][r]*=al;
      }
    }

    // --- PV ---
    #pragma unroll
    for (int kk=0;kk<2;++kk){
      short8 pa[2];
      #pragma unroll
      for (int mt=0;mt<2;++mt){
        int row = (mt<<4) + c;
        pa[mt] = *(const short8*)(plw + (((row<<7) + (kk<<6) + (g<<4)) ^ ((row&7)<<4)));
      }
      #pragma unroll
      for (int n=0;n<4;++n){
        int row = (n<<4) + c;
        short8 vf = *(const short8*)(vb_ + (((row<<7) + (kk<<6) + (g<<4)) ^ ((row&7)<<4)));
        o[0][n] = __builtin_amdgcn_mfma_f32_16x16x32_bf16(pa[0], vf, o[0][n], 0,0,0);
        o[1][n] = __builtin_amdgcn_mfma_f32_16x16x32_bf16(pa[1], vf, o[1][n], 0,0,0);
      }
    }

    // write next tile into the other buffer
    if (it < ntiles-1){
      #pragma unroll
      for (int u=0;u<2;++u){
        int ci = tid + (u<<8);
        *(uint4*)(kl + ((buf^1)<<13) + ci*16) = rk[u];
        *(uint4*)(vl + ((buf^1)<<13) + ci*16) = rv[u];
      }
    }
    __syncthreads();
  }

  // epilogue: unnormalized partials + (m, l)
  const int browbase = (b<<12) + tq0 + (w<<5);
  #pragma unroll
  for (int mt=0;mt<2;++mt){
    #pragma unroll
    for (int r=0;r<4;++r){
      float ls = lrow[mt][r];
      ls += __shfl_xor(ls,1);
      ls += __shfl_xor(ls,2);
      ls += __shfl_xor(ls,4);
      ls += __shfl_xor(ls,8);
      int grow = browbase + (mt<<4) + (g<<2) + r;
      if (c == 0){
        mpart[split*16384 + grow] = mrow[mt][r];
        lpart[split*16384 + grow] = ls;
      }
      #pragma unroll
      for (int n=0;n<4;++n)
        opart[((size_t)split<<20) + ((size_t)grow<<6) + (n<<4) + c] = o[mt][n][r];
    }
  }
}

// ---------------- kernel 3: combine the key-splits --------------------------
__global__ __launch_bounds__(256) void combine_k(const float* __restrict__ opart,
    const float* __restrict__ mpart, const float* __restrict__ lpart,
    float* __restrict__ out, int splits){
  int idx = blockIdx.x*256 + threadIdx.x;       // 0 .. 1048575
  int row = idx >> 6;
  float mm = -1e30f;
  for (int s=0;s<splits;++s) mm = fmaxf(mm, mpart[s*16384 + row]);
  float num = 0.f, den = 0.f;
  for (int s=0;s<splits;++s){
    float a = fexp2(mpart[s*16384 + row] - mm);
    num += opart[((size_t)s<<20) + idx] * a;
    den += lpart[s*16384 + row] * a;
  }
  out[idx] = num / den;
}

extern "C" void kernel_launch(void* const* d_in, const int* in_sizes, int n_in,
                              void* d_out, int out_size, void* d_ws, size_t ws_size,
                              hipStream_t stream){
  const float* x  = (const float*)d_in[0];
  const float* Wk = (const float*)d_in[1];
  const float* bk = (const float*)d_in[2];
  const float* Wq = (const float*)d_in[3];
  const float* bq = (const float*)d_in[4];
  const float* Wv = (const float*)d_in[5];
  unsigned char* ws = (unsigned char*)d_ws;
  // ws layout: wt | qw | kw | vtw | opart[splits] | mpart[splits] | lpart[splits]
  const size_t base = 131072 + 3u*2097152;              // 6,422,528
  const size_t per_split = 4194304u + 65536u + 65536u;  // opart + m + l
  int splits = 2;
  if      (ws_size >= base + 8*per_split) splits = 8;
  else if (ws_size >= base + 4*per_split) splits = 4;
  int ntiles = 64 / splits;

  unsigned short* wt  = (unsigned short*)(ws);
  unsigned short* qw  = (unsigned short*)(ws + 131072);
  unsigned short* kw  = (unsigned short*)(ws + 131072 + 2097152);
  unsigned short* vtw = (unsigned short*)(ws + 131072 + 2u*2097152);
  float* opart = (float*)(ws + base);
  float* mpart = (float*)(ws + base + (size_t)splits*4194304u);
  float* lpart = (float*)(ws + base + (size_t)splits*4194304u + (size_t)splits*65536u);
  float* out = (float*)d_out;

  hipLaunchKernelGGL(pack_w_k,   dim3(192),  dim3(256), 0, stream, Wk, Wq, Wv, wt);
  hipLaunchKernelGGL(qkv_proj_k, dim3(512),  dim3(256), 0, stream, x, bk, bq, wt, qw, kw, vtw);
  hipLaunchKernelGGL(attn_k,     dim3(128, splits), dim3(256), 0, stream,
                     qw, kw, vtw, opart, mpart, lpart, ntiles);
  hipLaunchKernelGGL(combine_k,  dim3(4096), dim3(256), 0, stream, opart, mpart, lpart, out, splits);
}